// Round 1
// baseline (115.434 us; speedup 1.0000x reference)
//
#include <hip/hip_runtime.h>

#define B_ 4
#define L_ 4096
#define D_ 64
#define N_ 16
#define CHUNK 8
#define NCHUNK (L_ / CHUNK)        // 512
#define TOTCHUNK (B_ * NCHUNK)     // 2048

constexpr float DT_  = 0.1f;
constexpr float EPS_ = 1e-6f;

// ---------------------------------------------------------------------------
// K1: fused projection + local chunk scan + LOCAL output + correction matrix.
// CHUNK=8 (was 16): 2048 blocks x 64 threads -> 8 waves/CU (2/SIMD), double
// the TLP of the previous version AND half the per-wave serial chains. The
// kernel was latency-bound (VALUBusy 11%, HBM 2.6%, Occ 10%), so both levers
// attack the same stall. Per block (= one 8-step chunk):
//   stage x -> LDS; 8 interleaved delta butterflies; Bm/Cm dots (W rows in
//   registers) -> a/g/cm in LDS; local scan with ZERO init writing the local
//   output directly; store chunk-final local state -> S; chunk decay -> Cdec;
//   and Wcor_l[n] = cm_l[n] * prod_{j<=l} a_j[n] so K3 can apply the init
//   correction without replaying the scan.
// ---------------------------------------------------------------------------
__global__ __launch_bounds__(64) void proj_scan_kernel(
    const float* __restrict__ x,  const float* __restrict__ A,
    const float* __restrict__ Wb, const float* __restrict__ bb,
    const float* __restrict__ Wc, const float* __restrict__ bc,
    const float* __restrict__ Wd, const float* __restrict__ bd,
    float* __restrict__ S, float* __restrict__ Cdec,
    float* __restrict__ Wcor, float* __restrict__ out)
{
    const int gc    = blockIdx.x;              // global chunk 0..2047
    const int batch = gc / NCHUNK;
    const int c     = gc % NCHUNK;
    const int lane  = threadIdx.x;
    const int base0 = batch * L_ + c * CHUNK;

    __shared__ float xs[CHUNK * D_];           // 2 KB
    __shared__ float ag[CHUNK * 32];           // 1 KB
    __shared__ float cm[CHUNK * N_];           // 512 B
    __shared__ float wbuf[CHUNK * N_];         // 512 B

    // ---- stage chunk's x (CHUNK*D_/4 = 128 float4, 2 per lane) ----
    const float4* xg  = (const float4*)(x + (size_t)base0 * D_);
    float4*       xsv = (float4*)xs;
    #pragma unroll
    for (int i = 0; i < (CHUNK * D_) / 256; i++) xsv[i * 64 + lane] = xg[i * 64 + lane];

    // ---- W rows in registers (overlaps x staging latency) ----
    const int o  = lane & 31;                  // 0-15 -> Bm row, 16-31 -> Cm row
    const int h2 = lane >> 5;                  // K-half
    float wreg[32];
    const float* Wrow = (o < 16) ? (Wb + o * D_) : (Wc + (o - 16) * D_);
    const float4* w4p = (const float4*)(Wrow + h2 * 32);
    #pragma unroll
    for (int j = 0; j < 8; j++) {
        float4 w4 = w4p[j];
        wreg[4*j+0] = w4.x; wreg[4*j+1] = w4.y;
        wreg[4*j+2] = w4.z; wreg[4*j+3] = w4.w;
    }
    const float wd   = Wd[lane];
    const float bd0  = bd[0];
    const float An   = A[lane & 15];           // row 0 of (D,N); rows identical
    const float bias = (o < 16) ? bb[o] : bc[o - 16];

    __syncthreads();

    // ---- deltas: CHUNK butterflies, interleaved so shfl chains pipeline ----
    float r[CHUNK];
    #pragma unroll
    for (int p = 0; p < CHUNK; p++) r[p] = xs[p * D_ + lane] * wd;
    #pragma unroll
    for (int m = 32; m >= 1; m >>= 1) {
        #pragma unroll
        for (int p = 0; p < CHUNK; p++) r[p] += __shfl_xor(r[p], m, 64);
    }
    float delta[CHUNK];
    #pragma unroll
    for (int p = 0; p < CHUNK; p++) {
        float z = r[p] + bd0;
        delta[p] = fmaxf(z, 0.0f) + log1pf(expf(-fabsf(z))) + DT_;
    }

    // ---- Bm/Cm dots -> LDS ----
    #pragma unroll
    for (int p = 0; p < CHUNK; p++) {
        float acc = 0.0f;
        const float4* xs4 = (const float4*)(xs + p * D_ + h2 * 32);
        #pragma unroll
        for (int j = 0; j < 8; j++) {
            float4 v = xs4[j];                 // broadcast LDS reads
            acc += v.x * wreg[4*j+0] + v.y * wreg[4*j+1]
                 + v.z * wreg[4*j+2] + v.w * wreg[4*j+3];
        }
        acc += __shfl_xor(acc, 32, 64);        // lanes 0-31 hold full dots
        if (lane < 16) {
            float Bm  = acc + bias;
            float tmp = An * delta[p];
            float a   = expf(tmp);
            float g   = (a - 1.0f) * delta[p] * Bm / (tmp + EPS_);
            ag[p * 32 + lane]      = a;
            ag[p * 32 + 16 + lane] = g;
        } else if (lane < 32) {
            cm[p * 16 + (lane - 16)] = acc + bias;
        }
    }
    __syncthreads();

    // ---- local scan (zero init) + local output, LDS-only inner loop ----
    float h[N_];
    #pragma unroll
    for (int n = 0; n < N_; n++) h[n] = 0.0f;
    #pragma unroll
    for (int s = 0; s < CHUNK; s++) {
        float xd = xs[s * D_ + lane];
        const float4* row = (const float4*)(ag + s * 32);
        const float4* crw = (const float4*)(cm + s * 16);
        float acc = 0.0f;
        #pragma unroll
        for (int q = 0; q < 4; q++) {
            float4 a4 = row[q];
            float4 g4 = row[4 + q];
            float4 c4 = crw[q];
            h[4*q+0] = a4.x * h[4*q+0] + g4.x * xd;  acc += c4.x * h[4*q+0];
            h[4*q+1] = a4.y * h[4*q+1] + g4.y * xd;  acc += c4.y * h[4*q+1];
            h[4*q+2] = a4.z * h[4*q+2] + g4.z * xd;  acc += c4.z * h[4*q+2];
            h[4*q+3] = a4.w * h[4*q+3] + g4.w * xd;  acc += c4.w * h[4*q+3];
        }
        out[(size_t)(base0 + s) * D_ + lane] = acc;   // local (zero-init) output
    }
    #pragma unroll
    for (int n = 0; n < N_; n++)
        S[(size_t)(gc * N_ + n) * D_ + lane] = h[n];  // chunk-final local state

    // ---- correction matrix + chunk decay (lanes 0..15, lane = n) ----
    if (lane < 16) {
        float cumn = 1.0f;
        #pragma unroll
        for (int s = 0; s < CHUNK; s++) {
            cumn *= ag[s * 32 + lane];                 // prod of a up to s incl.
            wbuf[s * 16 + lane] = cm[s * 16 + lane] * cumn;
        }
        Cdec[gc * N_ + lane] = cumn;
    }
    __syncthreads();
    // coalesced blast of wbuf -> global Wcor (CHUNK*N_ = 128 floats = 32 float4)
    if (lane < (CHUNK * N_) / 4)
        ((float4*)(Wcor + (size_t)base0 * 16))[lane] = ((const float4*)wbuf)[lane];
}

// ---------------------------------------------------------------------------
// K2: cross-chunk exclusive scan, 64 blocks x 64 threads; block = (b,n),
// thread = d. Groups of 32 with next-group prefetch: 64 loads in flight while
// a group is processed, so the serial chain runs nearly stall-free. NCHUNK is
// now 512 -> 16 groups (was 8); this kernel is small and absorbs the doubling.
// ---------------------------------------------------------------------------
#define G_ 32
__global__ __launch_bounds__(64) void combine(
    float* __restrict__ S, const float* __restrict__ Cdec)
{
    const int b = blockIdx.x >> 4;
    const int n = blockIdx.x & 15;
    const int d = threadIdx.x;
    const int cb = b * NCHUNK;

    float*       baseS = S    + (size_t)(cb * N_ + n) * D_ + d;  // stride N_*D_ per chunk
    const float* baseA = Cdec + cb * N_ + n;                     // stride N_ per chunk

    float run = 0.0f;
    float sbuf[G_], abuf[G_];
    #pragma unroll
    for (int j = 0; j < G_; j++) {
        sbuf[j] = baseS[(size_t)j * (N_ * D_)];
        abuf[j] = baseA[j * N_];
    }
    for (int cc = 0; cc < NCHUNK; cc += G_) {
        const int cn = (cc + G_ < NCHUNK) ? (cc + G_) : cc;   // last: dummy reload
        float t[G_], u[G_];
        #pragma unroll
        for (int j = 0; j < G_; j++) {
            t[j] = baseS[(size_t)(cn + j) * (N_ * D_)];
            u[j] = baseA[(cn + j) * N_];
        }
        #pragma unroll
        for (int j = 0; j < G_; j++) {
            baseS[(size_t)(cc + j) * (N_ * D_)] = run;        // exclusive prefix
            run = abuf[j] * run + sbuf[j];
        }
        #pragma unroll
        for (int j = 0; j < G_; j++) { sbuf[j] = t[j]; abuf[j] = u[j]; }
    }
}

// ---------------------------------------------------------------------------
// K3: apply correction: out[l,d] += sum_n Wcor_l[n] * init[n,d].
// 2048 blocks x 64 threads (8 waves/CU). The out rows are prefetched into
// registers BEFORE the sync so their ~HBM latency overlaps the Wcor/S loads;
// the final store writes oreg+acc (no scalar RMW re-read).
// ---------------------------------------------------------------------------
__global__ __launch_bounds__(64) void apply_kernel(
    const float* __restrict__ Wcor, const float* __restrict__ S,
    float* __restrict__ out)
{
    const int gc    = blockIdx.x;
    const int batch = gc / NCHUNK;
    const int c     = gc % NCHUNK;
    const int lane  = threadIdx.x;
    const int base0 = batch * L_ + c * CHUNK;

    __shared__ float wl[CHUNK * N_];           // 512 B

    // stage correction matrix (CHUNK*N_ = 128 floats = 32 float4)
    if (lane < (CHUNK * N_) / 4)
        ((float4*)wl)[lane] = ((const float4*)(Wcor + (size_t)base0 * 16))[lane];

    // chunk-initial state (post-combine S)
    float hi[N_];
    #pragma unroll
    for (int n = 0; n < N_; n++)
        hi[n] = S[(size_t)(gc * N_ + n) * D_ + lane];

    // prefetch local outputs (overlaps latency with wl/hi loads)
    float oreg[CHUNK];
    #pragma unroll
    for (int s = 0; s < CHUNK; s++)
        oreg[s] = out[(size_t)(base0 + s) * D_ + lane];

    __syncthreads();

    #pragma unroll
    for (int s = 0; s < CHUNK; s++) {
        const float4* crw = (const float4*)(wl + s * 16);
        float a = oreg[s];
        #pragma unroll
        for (int q = 0; q < 4; q++) {
            float4 w4 = crw[q];
            a += w4.x * hi[4*q+0] + w4.y * hi[4*q+1]
               + w4.z * hi[4*q+2] + w4.w * hi[4*q+3];
        }
        out[(size_t)(base0 + s) * D_ + lane] = a;
    }
}

// ---------------------------------------------------------------------------
extern "C" void kernel_launch(void* const* d_in, const int* in_sizes, int n_in,
                              void* d_out, int out_size, void* d_ws, size_t ws_size,
                              hipStream_t stream)
{
    const float* x  = (const float*)d_in[0];
    const float* A  = (const float*)d_in[1];
    const float* Wb = (const float*)d_in[2];
    const float* bb = (const float*)d_in[3];
    const float* Wc = (const float*)d_in[4];
    const float* bc = (const float*)d_in[5];
    const float* Wd = (const float*)d_in[6];
    const float* bd = (const float*)d_in[7];
    float* out = (float*)d_out;

    // ws carve (floats): S 2097152 (8MB) | Cdec 32768 | Wcor 262144 (1MB)
    float* S    = (float*)d_ws;
    float* Cdec = S    + (size_t)TOTCHUNK * N_ * D_;
    float* Wcor = Cdec + (size_t)TOTCHUNK * N_;

    proj_scan_kernel<<<TOTCHUNK, 64, 0, stream>>>(x, A, Wb, bb, Wc, bc, Wd, bd,
                                                  S, Cdec, Wcor, out);
    combine<<<B_ * N_, 64, 0, stream>>>(S, Cdec);
    apply_kernel<<<TOTCHUNK, 64, 0, stream>>>(Wcor, S, out);
}

// Round 2
// 100.257 us; speedup vs baseline: 1.1514x; 1.1514x over previous
//
#include <hip/hip_runtime.h>

#define B_ 4
#define L_ 4096
#define D_ 64
#define N_ 16
#define CHUNK 16
#define NCHUNK (L_ / CHUNK)        // 256
#define TOTCHUNK (B_ * NCHUNK)     // 1024

constexpr float DT_  = 0.1f;
constexpr float EPS_ = 1e-6f;

// ---------------------------------------------------------------------------
// K1: fused projection + local chunk scan + LOCAL output + correction matrix.
// NEW STRUCTURE: 1024 blocks x 256 threads (4 waves/chunk). Round-0 profile
// showed all 1-wave blocks co-resident (Occ 10% = ~4 waves/CU ceiling) but
// VALUBusy 11% -> each wave stalled ~90% on dependent LDS/shfl/exp latency
// with 1 wave/SIMD. Here the SAME chunk work is split across 4 waves:
//   - wave w computes deltas+dots+a/g/cm for steps s = 4w..4w+3  (chain/4)
//   - wave w runs the scan for states n = 4w..4w+3 over all 16 steps,
//     writing partial outputs (sum over its 4 n's) to LDS pout
//   - 256 threads reduce pout across the 4 waves -> out (local, zero-init)
// => 16 waves/CU (4/SIMD), per-wave serial chains ~4x shorter.
// ---------------------------------------------------------------------------
__global__ __launch_bounds__(256) void proj_scan_kernel(
    const float* __restrict__ x,  const float* __restrict__ A,
    const float* __restrict__ Wb, const float* __restrict__ bb,
    const float* __restrict__ Wc, const float* __restrict__ bc,
    const float* __restrict__ Wd, const float* __restrict__ bd,
    float* __restrict__ S, float* __restrict__ Cdec,
    float* __restrict__ Wcor, float* __restrict__ out)
{
    const int gc    = blockIdx.x;              // global chunk 0..1023
    const int batch = gc >> 8;                 // gc / NCHUNK
    const int c     = gc & (NCHUNK - 1);
    const int tid   = threadIdx.x;
    const int w     = tid >> 6;                // wave 0..3
    const int lane  = tid & 63;
    const int base0 = batch * L_ + c * CHUNK;

    __shared__ float xs[CHUNK * D_];           // 4 KB
    __shared__ float ag[CHUNK * 32];           // 2 KB  (a | g per step)
    __shared__ float cm[CHUNK * N_];           // 1 KB
    __shared__ float wbuf[CHUNK * N_];         // 1 KB
    __shared__ float pout[4 * CHUNK * D_];     // 16 KB (per-wave partial out)

    // ---- stage chunk's x: 256 float4, exactly one per thread ----
    ((float4*)xs)[tid] = ((const float4*)(x + (size_t)base0 * D_))[tid];

    // ---- W rows in registers (per-wave copy; overlaps x staging) ----
    const int o  = lane & 31;                  // 0-15 -> Bm row, 16-31 -> Cm row
    const int h2 = lane >> 5;                  // K-half
    float wreg[32];
    const float* Wrow = (o < 16) ? (Wb + o * D_) : (Wc + (o - 16) * D_);
    const float4* w4p = (const float4*)(Wrow + h2 * 32);
    #pragma unroll
    for (int j = 0; j < 8; j++) {
        float4 w4 = w4p[j];
        wreg[4*j+0] = w4.x; wreg[4*j+1] = w4.y;
        wreg[4*j+2] = w4.z; wreg[4*j+3] = w4.w;
    }
    const float wd   = Wd[lane];
    const float bd0  = bd[0];
    const float An   = A[lane & 15];           // row 0 of (D,N); rows identical
    const float bias = (o < 16) ? bb[o] : bc[o - 16];

    __syncthreads();

    // ---- deltas for THIS WAVE's 4 steps (s = 4w..4w+3) ----
    const int s0 = w * 4;
    float r[4];
    #pragma unroll
    for (int p = 0; p < 4; p++) r[p] = xs[(s0 + p) * D_ + lane] * wd;
    #pragma unroll
    for (int m = 32; m >= 1; m >>= 1) {
        #pragma unroll
        for (int p = 0; p < 4; p++) r[p] += __shfl_xor(r[p], m, 64);
    }
    float delta[4];
    #pragma unroll
    for (int p = 0; p < 4; p++) {
        float z = r[p] + bd0;
        delta[p] = fmaxf(z, 0.0f) + log1pf(expf(-fabsf(z))) + DT_;
    }

    // ---- Bm/Cm dots for this wave's 4 steps -> a/g/cm in LDS ----
    #pragma unroll
    for (int p = 0; p < 4; p++) {
        const int s = s0 + p;
        float acc = 0.0f;
        const float4* xs4 = (const float4*)(xs + s * D_ + h2 * 32);
        #pragma unroll
        for (int j = 0; j < 8; j++) {
            float4 v = xs4[j];                 // broadcast LDS reads
            acc += v.x * wreg[4*j+0] + v.y * wreg[4*j+1]
                 + v.z * wreg[4*j+2] + v.w * wreg[4*j+3];
        }
        acc += __shfl_xor(acc, 32, 64);        // lanes 0-31 hold full dots
        if (lane < 16) {
            float Bm  = acc + bias;
            float tmp = An * delta[p];
            float a   = expf(tmp);
            float g   = (a - 1.0f) * delta[p] * Bm / (tmp + EPS_);
            ag[s * 32 + lane]      = a;
            ag[s * 32 + 16 + lane] = g;
        } else if (lane < 32) {
            cm[s * 16 + (lane - 16)] = acc + bias;
        }
    }
    __syncthreads();

    // ---- scan: wave w owns states n = 4w..4w+3 over ALL 16 steps ----
    const int n0 = w * 4;
    float h0 = 0.0f, h1 = 0.0f, h2v = 0.0f, h3 = 0.0f;
    #pragma unroll
    for (int s = 0; s < CHUNK; s++) {
        float  xd = xs[s * D_ + lane];
        float4 a4 = *(const float4*)(ag + s * 32 + n0);       // broadcast
        float4 g4 = *(const float4*)(ag + s * 32 + 16 + n0);  // broadcast
        float4 c4 = *(const float4*)(cm + s * 16 + n0);       // broadcast
        h0 = a4.x * h0 + g4.x * xd;  float acc = c4.x * h0;
        h1 = a4.y * h1 + g4.y * xd;  acc += c4.y * h1;
        h2v = a4.z * h2v + g4.z * xd; acc += c4.z * h2v;
        h3 = a4.w * h3 + g4.w * xd;  acc += c4.w * h3;
        pout[(w * CHUNK + s) * D_ + lane] = acc;
    }
    // chunk-final local state for this wave's 4 n's
    S[(size_t)(gc * N_ + n0 + 0) * D_ + lane] = h0;
    S[(size_t)(gc * N_ + n0 + 1) * D_ + lane] = h1;
    S[(size_t)(gc * N_ + n0 + 2) * D_ + lane] = h2v;
    S[(size_t)(gc * N_ + n0 + 3) * D_ + lane] = h3;

    // ---- correction matrix + chunk decay (threads 0..15, tid = n) ----
    if (tid < 16) {
        float cumn = 1.0f;
        #pragma unroll
        for (int s = 0; s < CHUNK; s++) {
            cumn *= ag[s * 32 + tid];                 // prod of a up to s incl.
            wbuf[s * 16 + tid] = cm[s * 16 + tid] * cumn;
        }
        Cdec[gc * N_ + tid] = cumn;
    }
    __syncthreads();

    // ---- reduce partial outputs across the 4 waves -> out ----
    #pragma unroll
    for (int k = 0; k < 4; k++) {
        const int f = k * 256 + tid;                  // f = s*64 + d
        float v = pout[f] + pout[CHUNK * D_ + f]
                + pout[2 * CHUNK * D_ + f] + pout[3 * CHUNK * D_ + f];
        out[(size_t)base0 * D_ + f] = v;              // local (zero-init) output
    }
    // coalesced blast of wbuf -> global Wcor (256 floats = 64 float4)
    if (tid < 64)
        ((float4*)(Wcor + (size_t)base0 * 16))[tid] = ((const float4*)wbuf)[tid];
}

// ---------------------------------------------------------------------------
// K2: cross-chunk exclusive scan, 64 blocks x 64 threads; block = (b,n),
// thread = d. Back to NCHUNK=256 (round-0 config: 8 prefetch groups). Groups
// of 32 with next-group prefetch keep 64 loads in flight while a group's
// serial chain runs.
// ---------------------------------------------------------------------------
#define G_ 32
__global__ __launch_bounds__(64) void combine(
    float* __restrict__ S, const float* __restrict__ Cdec)
{
    const int b = blockIdx.x >> 4;
    const int n = blockIdx.x & 15;
    const int d = threadIdx.x;
    const int cb = b * NCHUNK;

    float*       baseS = S    + (size_t)(cb * N_ + n) * D_ + d;  // stride N_*D_ per chunk
    const float* baseA = Cdec + cb * N_ + n;                     // stride N_ per chunk

    float run = 0.0f;
    float sbuf[G_], abuf[G_];
    #pragma unroll
    for (int j = 0; j < G_; j++) {
        sbuf[j] = baseS[(size_t)j * (N_ * D_)];
        abuf[j] = baseA[j * N_];
    }
    for (int cc = 0; cc < NCHUNK; cc += G_) {
        const int cn = (cc + G_ < NCHUNK) ? (cc + G_) : cc;   // last: dummy reload
        float t[G_], u[G_];
        #pragma unroll
        for (int j = 0; j < G_; j++) {
            t[j] = baseS[(size_t)(cn + j) * (N_ * D_)];
            u[j] = baseA[(cn + j) * N_];
        }
        #pragma unroll
        for (int j = 0; j < G_; j++) {
            baseS[(size_t)(cc + j) * (N_ * D_)] = run;        // exclusive prefix
            run = abuf[j] * run + sbuf[j];
        }
        #pragma unroll
        for (int j = 0; j < G_; j++) { sbuf[j] = t[j]; abuf[j] = u[j]; }
    }
}

// ---------------------------------------------------------------------------
// K3: apply correction: out[l,d] += sum_n Wcor_l[n] * init[n,d].
// 1024 blocks x 256 threads: wave w applies steps s = 4w..4w+3. Each wave
// holds all 16 hi[n] (4x redundant loads, L2-broadcast) so there is no
// cross-wave reduction. out rows prefetched before the sync.
// ---------------------------------------------------------------------------
__global__ __launch_bounds__(256) void apply_kernel(
    const float* __restrict__ Wcor, const float* __restrict__ S,
    float* __restrict__ out)
{
    const int gc    = blockIdx.x;
    const int batch = gc >> 8;
    const int c     = gc & (NCHUNK - 1);
    const int tid   = threadIdx.x;
    const int w     = tid >> 6;
    const int lane  = tid & 63;
    const int base0 = batch * L_ + c * CHUNK;

    __shared__ float wl[CHUNK * N_];           // 1 KB

    // stage correction matrix (256 floats = 64 float4)
    if (tid < 64)
        ((float4*)wl)[tid] = ((const float4*)(Wcor + (size_t)base0 * 16))[tid];

    // chunk-initial state (post-combine S) — every wave loads all 16
    float hi[N_];
    #pragma unroll
    for (int n = 0; n < N_; n++)
        hi[n] = S[(size_t)(gc * N_ + n) * D_ + lane];

    // prefetch this wave's 4 out rows (overlaps latency with wl/hi loads)
    const int s0 = w * 4;
    float oreg[4];
    #pragma unroll
    for (int p = 0; p < 4; p++)
        oreg[p] = out[(size_t)(base0 + s0 + p) * D_ + lane];

    __syncthreads();

    #pragma unroll
    for (int p = 0; p < 4; p++) {
        const int s = s0 + p;
        const float4* crw = (const float4*)(wl + s * 16);
        float a = oreg[p];
        #pragma unroll
        for (int q = 0; q < 4; q++) {
            float4 w4 = crw[q];
            a += w4.x * hi[4*q+0] + w4.y * hi[4*q+1]
               + w4.z * hi[4*q+2] + w4.w * hi[4*q+3];
        }
        out[(size_t)(base0 + s) * D_ + lane] = a;
    }
}

// ---------------------------------------------------------------------------
extern "C" void kernel_launch(void* const* d_in, const int* in_sizes, int n_in,
                              void* d_out, int out_size, void* d_ws, size_t ws_size,
                              hipStream_t stream)
{
    const float* x  = (const float*)d_in[0];
    const float* A  = (const float*)d_in[1];
    const float* Wb = (const float*)d_in[2];
    const float* bb = (const float*)d_in[3];
    const float* Wc = (const float*)d_in[4];
    const float* bc = (const float*)d_in[5];
    const float* Wd = (const float*)d_in[6];
    const float* bd = (const float*)d_in[7];
    float* out = (float*)d_out;

    // ws carve (floats): S 1048576 (4MB) | Cdec 16384 | Wcor 262144 (1MB)
    float* S    = (float*)d_ws;
    float* Cdec = S    + (size_t)TOTCHUNK * N_ * D_;
    float* Wcor = Cdec + (size_t)TOTCHUNK * N_;

    proj_scan_kernel<<<TOTCHUNK, 256, 0, stream>>>(x, A, Wb, bb, Wc, bc, Wd, bd,
                                                   S, Cdec, Wcor, out);
    combine<<<B_ * N_, 64, 0, stream>>>(S, Cdec);
    apply_kernel<<<TOTCHUNK, 256, 0, stream>>>(Wcor, S, out);
}